// Round 5
// baseline (224.109 us; speedup 1.0000x reference)
//
#include <hip/hip_runtime.h>
#include <math.h>

#define N_NODES 100000
#define E_EDGES 1600000
#define F_DIM   48
#define NF      (N_NODES * F_DIM)
#define AVG_LOG 2.8332133440562162f   /* ln(17) */
#define PNA_EPS 1e-5f
#define CAP     64   /* max bucket size; P(any node deg >= 64) ~ 1e-14 for Poisson(16) */

typedef float f32x4 __attribute__((ext_vector_type(4)));

// ---------------- kernel 1: zero counters ----------------
__global__ void k_zero(unsigned* __restrict__ cnt) {
    int i = blockIdx.x * blockDim.x + threadIdx.x;
    if (i < N_NODES) cnt[i] = 0u;
}

// ---------------- kernel 2: bucket-fill edge ids, 4 edges/thread ----------------
__global__ void k_fill(const int4* __restrict__ index4, unsigned* __restrict__ cnt,
                       unsigned* __restrict__ eids) {
    int t = blockIdx.x * blockDim.x + threadIdx.x;
    if (t >= E_EDGES / 4) return;
    int4 idx = index4[t];
    unsigned e0 = (unsigned)t * 4u;

    unsigned p0 = atomicAdd(&cnt[idx.x], 1u);
    if (p0 < CAP) eids[(unsigned)idx.x * CAP + p0] = e0 + 0u;
    unsigned p1 = atomicAdd(&cnt[idx.y], 1u);
    if (p1 < CAP) eids[(unsigned)idx.y * CAP + p1] = e0 + 1u;
    unsigned p2 = atomicAdd(&cnt[idx.z], 1u);
    if (p2 < CAP) eids[(unsigned)idx.z * CAP + p2] = e0 + 2u;
    unsigned p3 = atomicAdd(&cnt[idx.w], 1u);
    if (p3 < CAP) eids[(unsigned)idx.w * CAP + p3] = e0 + 3u;
}

// ---------------- kernel 3: gather + segmented reduce + finalize ----------------
// 12 threads per node; thread g owns features [4g, 4g+4)
__global__ __launch_bounds__(256) void k_reduce(const f32x4* __restrict__ x4,
                                                const unsigned* __restrict__ eids,
                                                const unsigned* __restrict__ cnt,
                                                const float* __restrict__ w,
                                                float* __restrict__ out) {
    int t = blockIdx.x * blockDim.x + threadIdx.x;
    if (t >= N_NODES * 12) return;
    int n = t / 12;
    int g = t - n * 12;

    const unsigned* eb  = eids + (unsigned)n * CAP;
    const uint4*    eb4 = (const uint4*)eb;  // bucket base is 256B-aligned
    unsigned d = cnt[n];
    if (d > CAP) d = CAP;  // safety clamp (never triggers for this dataset)

    float sx = 0.f, sy = 0.f, sz = 0.f, sw = 0.f;
    float qx = 0.f, qy = 0.f, qz = 0.f, qw = 0.f;
    float mnx =  INFINITY, mny =  INFINITY, mnz =  INFINITY, mnw =  INFINITY;
    float mxx = -INFINITY, mxy = -INFINITY, mxz = -INFINITY, mxw = -INFINITY;

#define ACC(v)                                                                 \
    do {                                                                       \
        sx += (v)[0]; sy += (v)[1]; sz += (v)[2]; sw += (v)[3];                \
        qx += (v)[0] * (v)[0]; qy += (v)[1] * (v)[1];                          \
        qz += (v)[2] * (v)[2]; qw += (v)[3] * (v)[3];                          \
        mnx = fminf(mnx, (v)[0]); mny = fminf(mny, (v)[1]);                    \
        mnz = fminf(mnz, (v)[2]); mnw = fminf(mnw, (v)[3]);                    \
        mxx = fmaxf(mxx, (v)[0]); mxy = fmaxf(mxy, (v)[1]);                    \
        mxz = fmaxf(mxz, (v)[2]); mxw = fmaxf(mxw, (v)[3]);                    \
    } while (0)

    unsigned i = 0;
    for (; i + 8 <= d; i += 8) {
        uint4 a = eb4[i >> 2];
        uint4 b = eb4[(i >> 2) + 1];
        f32x4 v0 = __builtin_nontemporal_load(&x4[a.x * 12u + (unsigned)g]);
        f32x4 v1 = __builtin_nontemporal_load(&x4[a.y * 12u + (unsigned)g]);
        f32x4 v2 = __builtin_nontemporal_load(&x4[a.z * 12u + (unsigned)g]);
        f32x4 v3 = __builtin_nontemporal_load(&x4[a.w * 12u + (unsigned)g]);
        f32x4 v4 = __builtin_nontemporal_load(&x4[b.x * 12u + (unsigned)g]);
        f32x4 v5 = __builtin_nontemporal_load(&x4[b.y * 12u + (unsigned)g]);
        f32x4 v6 = __builtin_nontemporal_load(&x4[b.z * 12u + (unsigned)g]);
        f32x4 v7 = __builtin_nontemporal_load(&x4[b.w * 12u + (unsigned)g]);
        ACC(v0); ACC(v1); ACC(v2); ACC(v3); ACC(v4); ACC(v5); ACC(v6); ACC(v7);
    }
    for (; i + 4 <= d; i += 4) {
        uint4 a = eb4[i >> 2];
        f32x4 v0 = __builtin_nontemporal_load(&x4[a.x * 12u + (unsigned)g]);
        f32x4 v1 = __builtin_nontemporal_load(&x4[a.y * 12u + (unsigned)g]);
        f32x4 v2 = __builtin_nontemporal_load(&x4[a.z * 12u + (unsigned)g]);
        f32x4 v3 = __builtin_nontemporal_load(&x4[a.w * 12u + (unsigned)g]);
        ACC(v0); ACC(v1); ACC(v2); ACC(v3);
    }
    for (; i < d; ++i) {
        unsigned e = eb[i];
        f32x4 v = __builtin_nontemporal_load(&x4[e * 12u + (unsigned)g]);
        ACC(v);
    }
#undef ACC

    float df = (float)d;
    float sd = fmaxf(df, 1.0f);
    float inv = 1.0f / sd;

    if (d == 0u) {
        mnx = mny = mnz = mnw = 0.f;
        mxx = mxy = mxz = mxw = 0.f;
    }

    float logdeg = logf(df + 1.0f);
    float amp = logdeg * (1.0f / AVG_LOG);
    float att = (d > 0u) ? (AVG_LOG / logdeg) : 0.0f;

    // fold scalers into per-aggregator coefficients: k = a*3 + s
    float c_mean = w[0] + w[1]  * amp + w[2]  * att;
    float c_min  = w[3] + w[4]  * amp + w[5]  * att;
    float c_max  = w[6] + w[7]  * amp + w[8]  * att;
    float c_std  = w[9] + w[10] * amp + w[11] * att;

    f32x4 o;
    {
        float mean = sx * inv;
        float var  = fmaxf(qx * inv - mean * mean, 0.0f);
        o[0] = mean * c_mean + mnx * c_min + mxx * c_max + sqrtf(var + PNA_EPS) * c_std;
    }
    {
        float mean = sy * inv;
        float var  = fmaxf(qy * inv - mean * mean, 0.0f);
        o[1] = mean * c_mean + mny * c_min + mxy * c_max + sqrtf(var + PNA_EPS) * c_std;
    }
    {
        float mean = sz * inv;
        float var  = fmaxf(qz * inv - mean * mean, 0.0f);
        o[2] = mean * c_mean + mnz * c_min + mxz * c_max + sqrtf(var + PNA_EPS) * c_std;
    }
    {
        float mean = sw * inv;
        float var  = fmaxf(qw * inv - mean * mean, 0.0f);
        o[3] = mean * c_mean + mnw * c_min + mxw * c_max + sqrtf(var + PNA_EPS) * c_std;
    }

    ((f32x4*)out)[n * 12 + g] = o;
}

extern "C" void kernel_launch(void* const* d_in, const int* in_sizes, int n_in,
                              void* d_out, int out_size, void* d_ws, size_t ws_size,
                              hipStream_t stream) {
    const f32x4* x4    = (const f32x4*)d_in[0];
    const int4*  index4 = (const int4*)d_in[1];
    const float* w     = (const float*)d_in[3];
    float* out = (float*)d_out;

    // workspace layout
    char* ws = (char*)d_ws;
    unsigned* cnt  = (unsigned*)(ws);                        // N
    unsigned* eids = (unsigned*)(ws + (size_t)N_NODES * 4);  // N * CAP (16B-aligned: 400000 % 16 == 0)

    const int B = 256;
    k_zero<<<(N_NODES + B - 1) / B, B, 0, stream>>>(cnt);
    k_fill<<<(E_EDGES / 4 + B - 1) / B, B, 0, stream>>>(index4, cnt, eids);
    k_reduce<<<(N_NODES * 12 + B - 1) / B, B, 0, stream>>>(x4, eids, cnt, w, out);
}

// Round 6
// 209.227 us; speedup vs baseline: 1.0711x; 1.0711x over previous
//
#include <hip/hip_runtime.h>
#include <math.h>

#define N_NODES 100000
#define E_EDGES 1600000
#define F_DIM   48
#define NF      (N_NODES * F_DIM)
#define AVG_LOG 2.8332133440562162f   /* ln(17) */
#define PNA_EPS 1e-5f
#define CAP     64   /* max bucket size; P(any node deg >= 64) ~ 1e-14 for Poisson(16) */

typedef float f32x4 __attribute__((ext_vector_type(4)));

// ---------------- kernel 1: bucket-fill edge ids (1 edge/thread, r4-proven) ----------------
__global__ void k_fill(const int* __restrict__ index, unsigned* __restrict__ cnt,
                       unsigned* __restrict__ eids) {
    int e = blockIdx.x * blockDim.x + threadIdx.x;
    if (e >= E_EDGES) return;
    int node = index[e];
    unsigned pos = atomicAdd(&cnt[node], 1u);
    if (pos < CAP) eids[(unsigned)node * CAP + pos] = (unsigned)e;
}

// ---------------- kernel 2: gather + segmented reduce + finalize ----------------
// 12 threads per node; thread g owns features [4g, 4g+4)
__global__ __launch_bounds__(256) void k_reduce(const f32x4* __restrict__ x4,
                                                const unsigned* __restrict__ eids,
                                                const unsigned* __restrict__ cnt,
                                                const float* __restrict__ w,
                                                float* __restrict__ out) {
    int t = blockIdx.x * blockDim.x + threadIdx.x;
    if (t >= N_NODES * 12) return;
    int n = t / 12;
    int g = t - n * 12;

    const unsigned* eb  = eids + (unsigned)n * CAP;
    const uint4*    eb4 = (const uint4*)eb;  // bucket base is 256B-aligned
    unsigned d = cnt[n];
    if (d > CAP) d = CAP;  // safety clamp (never triggers for this dataset)

    float sx = 0.f, sy = 0.f, sz = 0.f, sw = 0.f;
    float qx = 0.f, qy = 0.f, qz = 0.f, qw = 0.f;
    float mnx =  INFINITY, mny =  INFINITY, mnz =  INFINITY, mnw =  INFINITY;
    float mxx = -INFINITY, mxy = -INFINITY, mxz = -INFINITY, mxw = -INFINITY;

#define ACC(v)                                                                 \
    do {                                                                       \
        sx += (v)[0]; sy += (v)[1]; sz += (v)[2]; sw += (v)[3];                \
        qx += (v)[0] * (v)[0]; qy += (v)[1] * (v)[1];                          \
        qz += (v)[2] * (v)[2]; qw += (v)[3] * (v)[3];                          \
        mnx = fminf(mnx, (v)[0]); mny = fminf(mny, (v)[1]);                    \
        mnz = fminf(mnz, (v)[2]); mnw = fminf(mnw, (v)[3]);                    \
        mxx = fmaxf(mxx, (v)[0]); mxy = fmaxf(mxy, (v)[1]);                    \
        mxz = fmaxf(mxz, (v)[2]); mxw = fmaxf(mxw, (v)[3]);                    \
    } while (0)

    unsigned i = 0;
    for (; i + 4 <= d; i += 4) {
        uint4 a = eb4[i >> 2];
        f32x4 v0 = x4[a.x * 12u + (unsigned)g];
        f32x4 v1 = x4[a.y * 12u + (unsigned)g];
        f32x4 v2 = x4[a.z * 12u + (unsigned)g];
        f32x4 v3 = x4[a.w * 12u + (unsigned)g];
        ACC(v0); ACC(v1); ACC(v2); ACC(v3);
    }
    for (; i < d; ++i) {
        unsigned e = eb[i];
        f32x4 v = x4[e * 12u + (unsigned)g];
        ACC(v);
    }
#undef ACC

    float df = (float)d;
    float sd = fmaxf(df, 1.0f);
    float inv = 1.0f / sd;

    if (d == 0u) {
        mnx = mny = mnz = mnw = 0.f;
        mxx = mxy = mxz = mxw = 0.f;
    }

    float logdeg = logf(df + 1.0f);
    float amp = logdeg * (1.0f / AVG_LOG);
    float att = (d > 0u) ? (AVG_LOG / logdeg) : 0.0f;

    // fold scalers into per-aggregator coefficients: k = a*3 + s
    float c_mean = w[0] + w[1]  * amp + w[2]  * att;
    float c_min  = w[3] + w[4]  * amp + w[5]  * att;
    float c_max  = w[6] + w[7]  * amp + w[8]  * att;
    float c_std  = w[9] + w[10] * amp + w[11] * att;

    f32x4 o;
    {
        float mean = sx * inv;
        float var  = fmaxf(qx * inv - mean * mean, 0.0f);
        o[0] = mean * c_mean + mnx * c_min + mxx * c_max + sqrtf(var + PNA_EPS) * c_std;
    }
    {
        float mean = sy * inv;
        float var  = fmaxf(qy * inv - mean * mean, 0.0f);
        o[1] = mean * c_mean + mny * c_min + mxy * c_max + sqrtf(var + PNA_EPS) * c_std;
    }
    {
        float mean = sz * inv;
        float var  = fmaxf(qz * inv - mean * mean, 0.0f);
        o[2] = mean * c_mean + mnz * c_min + mxz * c_max + sqrtf(var + PNA_EPS) * c_std;
    }
    {
        float mean = sw * inv;
        float var  = fmaxf(qw * inv - mean * mean, 0.0f);
        o[3] = mean * c_mean + mnw * c_min + mxw * c_max + sqrtf(var + PNA_EPS) * c_std;
    }

    ((f32x4*)out)[n * 12 + g] = o;
}

extern "C" void kernel_launch(void* const* d_in, const int* in_sizes, int n_in,
                              void* d_out, int out_size, void* d_ws, size_t ws_size,
                              hipStream_t stream) {
    const f32x4* x4    = (const f32x4*)d_in[0];
    const int*   index = (const int*)d_in[1];
    const float* w     = (const float*)d_in[3];
    float* out = (float*)d_out;

    // workspace layout
    char* ws = (char*)d_ws;
    unsigned* cnt  = (unsigned*)(ws);                        // N
    unsigned* eids = (unsigned*)(ws + (size_t)N_NODES * 4);  // N * CAP (256B-aligned buckets)

    const int B = 256;
    hipMemsetAsync(cnt, 0, (size_t)N_NODES * 4, stream);
    k_fill<<<(E_EDGES + B - 1) / B, B, 0, stream>>>(index, cnt, eids);
    k_reduce<<<(N_NODES * 12 + B - 1) / B, B, 0, stream>>>(x4, eids, cnt, w, out);
}